// Round 5
// baseline (22471.242 us; speedup 1.0000x reference)
//
#include <hip/hip_runtime.h>
#include <stdint.h>

#define AGENT __HIP_MEMORY_SCOPE_AGENT
typedef unsigned long long u64;

// x[64][256][256] -> xT[t][iq][b][4]   (packed quads of input dim, batch-minor)
__global__ __launch_bounds__(256) void xpose_in(const float* __restrict__ x,
                                                float* __restrict__ xT) {
  const int t = blockIdx.x;
  const int b = threadIdx.x & 63;
  const int w = threadIdx.x >> 6;
  const float* xr = x + ((size_t)b * 256 + t) * 256;
  float* o = xT + (size_t)t * 64 * 256;
  for (int iq = w * 16; iq < w * 16 + 16; ++iq) {
    float4 v = *(const float4*)(xr + iq * 4);
    *(float4*)(o + ((size_t)iq * 64 + b) * 4) = v;
  }
}

// Pack [W;U] ([KT][4H], col cg) into wuT[cg][k] (transpose, coalesced both sides)
__global__ __launch_bounds__(256) void pack_wu(const float* __restrict__ W,
                                               const float* __restrict__ U,
                                               float* __restrict__ out,
                                               int DIN, int H) {
  __shared__ float tile[64][65];
  const int KT = DIN + H;
  const int c0 = blockIdx.x * 64;
  const int k0 = blockIdx.y * 64;
  const int tx = threadIdx.x & 63;
  const int ty = threadIdx.x >> 6;
  for (int r = ty; r < 64; r += 4) {
    const int k = k0 + r;
    tile[r][tx] = (k < DIN) ? W[(size_t)k * (4 * H) + c0 + tx]
                            : U[(size_t)(k - DIN) * (4 * H) + c0 + tx];
  }
  __syncthreads();
  for (int r = ty; r < 64; r += 4) {
    out[(size_t)(c0 + r) * KT + k0 + tx] = tile[tx][r];
  }
}

// Accumulate QW quads (this wave's K-slice) of src into acc[32] (4 gates x 8
// units). src layout: [quad][64][4]. wr[g] = row base for gate g (unit u at
// +u*KT). Plain cached loads (L2 dedups the cross-WG broadcast); chunked
// double-buffer to cover L2/LLC latency.
template <int QW, int CH, int KT>
__device__ __forceinline__ void accum8(const float* __restrict__ src, int q0,
                                       int kof0, const float* const wr[4],
                                       int lane, float acc[32]) {
  constexpr int NCH = QW / CH;
  float4 cur[CH], nxt[CH];
#pragma unroll
  for (int i = 0; i < CH; ++i)
    cur[i] = *(const float4*)(src + (size_t)(q0 + i) * 256 + lane * 4);
  for (int ch = 0; ch < NCH; ++ch) {
    const int qb = q0 + ch * CH;
    if (ch + 1 < NCH) {
#pragma unroll
      for (int i = 0; i < CH; ++i)
        nxt[i] = *(const float4*)(src + (size_t)(qb + CH + i) * 256 + lane * 4);
    }
#pragma unroll
    for (int i = 0; i < CH; ++i) {
      const int kof = kof0 + 4 * (qb + i);
      const float4 xv = cur[i];
#pragma unroll
      for (int g = 0; g < 4; ++g) {
#pragma unroll
        for (int u = 0; u < 8; ++u) {
          const float4 w = *(const float4*)(wr[g] + (size_t)u * KT + kof);
          float& a = acc[g * 8 + u];
          a = fmaf(w.x, xv.x, a);
          a = fmaf(w.y, xv.y, a);
          a = fmaf(w.z, xv.z, a);
          a = fmaf(w.w, xv.w, a);
        }
      }
    }
#pragma unroll
    for (int i = 0; i < CH; ++i) cur[i] = nxt[i];
  }
}

// One pipelined LSTM layer. 512-thread WG owns 8 hidden units (2 quads).
// lane = batch; 8 waves split K 8-ways; wave u also owns unit u's gates.
// Sync: coherent flags; bulk h data via normal cached loads (safe: lines are
// write-once per launch, only touched after the producer's flag; dispatch
// acquire invalidates stale L2 across graph replays).
template <int DIN, int H, int NWG, int NWGP, bool FIN, bool XCOH>
__device__ __forceinline__ void layer_body(
    int wg, int tid, const float* __restrict__ xin, float* __restrict__ hseq,
    const float* __restrict__ wuT, const float* __restrict__ bias,
    float* __restrict__ dout, unsigned* __restrict__ selfF,
    unsigned* __restrict__ prevF, float (*sZ)[32][64], float* sH) {
  constexpr int NQ2 = H / 4;
  constexpr int KT = DIN + H;
  constexpr int QW1 = DIN / 32;  // x-slice quads per wave
  constexpr int QW2 = H / 32;    // h-slice quads per wave
  constexpr int CH1 = (QW1 % 4 == 0) ? 4 : 2;
  constexpr int CH2 = (QW2 % 4 == 0) ? 4 : 2;
  constexpr int T = 256;

  const int lane = tid & 63;
  const int wv = tid >> 6;  // 0..7

  const float* wr[4];
#pragma unroll
  for (int g = 0; g < 4; ++g) wr[g] = wuT + ((size_t)(g * H + wg * 8)) * KT;

  float bz[4];
#pragma unroll
  for (int g = 0; g < 4; ++g) bz[g] = bias[g * H + wg * 8 + wv];

  float cst = 0.f;

  for (int t = 0; t < T; ++t) {
    float acc[32];
#pragma unroll
    for (int c = 0; c < 32; ++c) acc[c] = 0.f;

    if (!XCOH) {
      // layer 0: x static — overlap input projection with waiting peers
      accum8<QW1, CH1, KT>(xin + (size_t)t * (DIN / 4) * 256, wv * QW1, 0, wr,
                           lane, acc);
    }
    // wave 0 polls self flags (t-1); wave 1 polls producer flags (t)
    if (t > 0 && wv == 0 && lane < NWG) {
      while (__hip_atomic_load(&selfF[(t - 1) * NWG + lane], __ATOMIC_RELAXED,
                               AGENT) == 0u) {
        __builtin_amdgcn_s_sleep(4);
      }
    }
    if (XCOH && wv == 1 && lane < NWGP) {
      while (__hip_atomic_load(&prevF[t * NWGP + lane], __ATOMIC_RELAXED,
                               AGENT) == 0u) {
        __builtin_amdgcn_s_sleep(4);
      }
    }
    __syncthreads();
    asm volatile("" ::: "memory");  // no compiler hoist of loads above polls

    if (XCOH) {
      accum8<QW1, CH1, KT>(xin + (size_t)t * (DIN / 4) * 256, wv * QW1, 0, wr,
                           lane, acc);
    }
    if (t > 0) {
      accum8<QW2, CH2, KT>(hseq + (size_t)(t - 1) * NQ2 * 256, wv * QW2, DIN,
                           wr, lane, acc);
    }

    // 8-way K-split reduction
#pragma unroll
    for (int c = 0; c < 32; ++c) sZ[wv][c][lane] = acc[c];
    __syncthreads();

    float z[4];
#pragma unroll
    for (int g = 0; g < 4; ++g) {
      z[g] = bz[g];
#pragma unroll
      for (int k = 0; k < 8; ++k) z[g] += sZ[k][g * 8 + wv][lane];
    }
    const float ig = 1.f / (1.f + __expf(-z[0]));
    const float fg = 1.f / (1.f + __expf(-z[1]));
    const float gg = FIN ? tanhf(z[2]) : fmaxf(z[2], 0.f);
    const float og = 1.f / (1.f + __expf(-z[3]));
    cst = fg * cst + ig * gg;
    const float ca = FIN ? tanhf(cst) : fmaxf(cst, 0.f);
    const float h = og * ca;
    sH[lane * 8 + wv] = h;  // [b][u]
    if (FIN && t == T - 1) dout[(size_t)lane * H + wg * 8 + wv] = h;
    __syncthreads();

    // waves 0,1 publish the WG's two 1 KB h-quads (agent write-through), signal
    if (wv < 2) {
      const float4 v = *(const float4*)&sH[lane * 8 + wv * 4];
      float* hw = hseq + (size_t)t * NQ2 * 256 + (size_t)(wg * 2 + wv) * 256 +
                  lane * 4;
      const u64 lo = ((u64)__float_as_uint(v.y) << 32) | __float_as_uint(v.x);
      const u64 hi = ((u64)__float_as_uint(v.w) << 32) | __float_as_uint(v.z);
      __hip_atomic_store((u64*)hw, lo, __ATOMIC_RELAXED, AGENT);
      __hip_atomic_store((u64*)hw + 1, hi, __ATOMIC_RELAXED, AGENT);
      asm volatile("s_waitcnt vmcnt(0)" ::: "memory");
    }
    __syncthreads();
    if (tid == 0)
      __hip_atomic_store(&selfF[t * NWG + wg], 1u, __ATOMIC_RELAXED, AGENT);
  }
}

__global__ __launch_bounds__(512) void lstm_fused(
    const float* __restrict__ xT, float* __restrict__ h0,
    float* __restrict__ h1, float* __restrict__ h2, float* __restrict__ h3,
    float* __restrict__ h4, float* __restrict__ h5,
    const float* __restrict__ wuT0, const float* __restrict__ wuT1,
    const float* __restrict__ wuT2, const float* __restrict__ wuT3,
    const float* __restrict__ wuT4, const float* __restrict__ wuT5,
    const float* __restrict__ b0, const float* __restrict__ b1,
    const float* __restrict__ b2, const float* __restrict__ b3,
    const float* __restrict__ b4, const float* __restrict__ b5,
    float* __restrict__ dout, unsigned* __restrict__ f0,
    unsigned* __restrict__ f1, unsigned* __restrict__ f2,
    unsigned* __restrict__ f3, unsigned* __restrict__ f4,
    unsigned* __restrict__ f5) {
  __shared__ float sZ[8][32][64];
  __shared__ float sH[512];
  const int b = blockIdx.x;
  const int tid = threadIdx.x;
  // heavy layers (L0, L4) first so they land one-per-CU
  if (b < 64) {
    layer_body<256, 512, 64, 0, false, false>(b, tid, xT, h0, wuT0, b0, nullptr,
                                              f0, nullptr, sZ, sH);
  } else if (b < 128) {
    layer_body<256, 512, 64, 32, false, true>(b - 64, tid, h3, h4, wuT4, b4,
                                              nullptr, f4, f3, sZ, sH);
  } else if (b < 160) {
    layer_body<512, 256, 32, 64, false, true>(b - 128, tid, h0, h1, wuT1, b1,
                                              nullptr, f1, f0, sZ, sH);
  } else if (b < 192) {
    layer_body<64, 256, 32, 8, false, true>(b - 160, tid, h2, h3, wuT3, b3,
                                            nullptr, f3, f2, sZ, sH);
  } else if (b < 224) {
    layer_body<512, 256, 32, 64, true, true>(b - 192, tid, h4, h5, wuT5, b5,
                                             dout, f5, f4, sZ, sH);
  } else {
    layer_body<256, 64, 8, 32, false, true>(b - 224, tid, h1, h2, wuT2, b2,
                                            nullptr, f2, f1, sZ, sH);
  }
}

extern "C" void kernel_launch(void* const* d_in, const int* in_sizes, int n_in,
                              void* d_out, int out_size, void* d_ws,
                              size_t ws_size, hipStream_t stream) {
  (void)in_sizes; (void)n_in; (void)out_size; (void)ws_size;
  const float* x = (const float*)d_in[0];
  const float* W[6];
  const float* U[6];
  const float* B[6];
  for (int l = 0; l < 6; ++l) {
    W[l] = (const float*)d_in[1 + 3 * l];
    U[l] = (const float*)d_in[2 + 3 * l];
    B[l] = (const float*)d_in[3 + 3 * l];
  }
  char* ws = (char*)d_ws;
  // flags: [T][NWG] per layer; NWG = 64,32,8,32,64,32
  unsigned* f0 = (unsigned*)ws;
  unsigned* f1 = f0 + 64 * 256;
  unsigned* f2 = f1 + 32 * 256;
  unsigned* f3 = f2 + 8 * 256;
  unsigned* f4 = f3 + 32 * 256;
  unsigned* f5 = f4 + 64 * 256;
  float* wuT0 = (float*)(ws + (1u << 20));
  float* wuT1 = wuT0 + (size_t)2048 * 768;
  float* wuT2 = wuT1 + (size_t)1024 * 768;
  float* wuT3 = wuT2 + (size_t)256 * 320;
  float* wuT4 = wuT3 + (size_t)1024 * 320;
  float* wuT5 = wuT4 + (size_t)2048 * 768;
  float* xT = (float*)(ws + (22u << 20));   // 16 MB
  float* h0 = (float*)(ws + (38u << 20));   // 32 MB
  float* h1 = (float*)(ws + (70u << 20));   // 16 MB
  float* h2 = (float*)(ws + (86u << 20));   // 4 MB
  float* h3 = (float*)(ws + (90u << 20));   // 16 MB
  float* h4 = (float*)(ws + (106u << 20));  // 32 MB
  float* h5 = (float*)(ws + (138u << 20));  // 16 MB (full T, no ring)

  hipMemsetAsync(f0, 0, 232 * 256 * sizeof(unsigned), stream);
  xpose_in<<<256, 256, 0, stream>>>(x, xT);
  pack_wu<<<dim3(32, 12), 256, 0, stream>>>(W[0], U[0], wuT0, 256, 512);
  pack_wu<<<dim3(16, 12), 256, 0, stream>>>(W[1], U[1], wuT1, 512, 256);
  pack_wu<<<dim3(4, 5), 256, 0, stream>>>(W[2], U[2], wuT2, 256, 64);
  pack_wu<<<dim3(16, 5), 256, 0, stream>>>(W[3], U[3], wuT3, 64, 256);
  pack_wu<<<dim3(32, 12), 256, 0, stream>>>(W[4], U[4], wuT4, 256, 512);
  pack_wu<<<dim3(16, 12), 256, 0, stream>>>(W[5], U[5], wuT5, 512, 256);

  lstm_fused<<<232, 512, 0, stream>>>(xT, h0, h1, h2, h3, h4, h5, wuT0, wuT1,
                                      wuT2, wuT3, wuT4, wuT5, B[0], B[1], B[2],
                                      B[3], B[4], B[5], (float*)d_out, f0, f1,
                                      f2, f3, f4, f5);
}

// Round 7
// 20135.088 us; speedup vs baseline: 1.1160x; 1.1160x over previous
//
#include <hip/hip_runtime.h>
#include <stdint.h>

#define AGENT __HIP_MEMORY_SCOPE_AGENT
typedef unsigned long long u64;

// x[64][256][256] -> xT[t][iq][b][4]   (packed quads of input dim, batch-minor)
__global__ __launch_bounds__(256) void xpose_in(const float* __restrict__ x,
                                                float* __restrict__ xT) {
  const int t = blockIdx.x;
  const int b = threadIdx.x & 63;
  const int w = threadIdx.x >> 6;
  const float* xr = x + ((size_t)b * 256 + t) * 256;
  float* o = xT + (size_t)t * 64 * 256;
  for (int iq = w * 16; iq < w * 16 + 16; ++iq) {
    float4 v = *(const float4*)(xr + iq * 4);
    *(float4*)(o + ((size_t)iq * 64 + b) * 4) = v;
  }
}

// Pack [W;U] ([KT][4H], col cg) into wuT[cg][k] (transpose, coalesced both sides)
__global__ __launch_bounds__(256) void pack_wu(const float* __restrict__ W,
                                               const float* __restrict__ U,
                                               float* __restrict__ out,
                                               int DIN, int H) {
  __shared__ float tile[64][65];
  const int KT = DIN + H;
  const int c0 = blockIdx.x * 64;
  const int k0 = blockIdx.y * 64;
  const int tx = threadIdx.x & 63;
  const int ty = threadIdx.x >> 6;
  for (int r = ty; r < 64; r += 4) {
    const int k = k0 + r;
    tile[r][tx] = (k < DIN) ? W[(size_t)k * (4 * H) + c0 + tx]
                            : U[(size_t)(k - DIN) * (4 * H) + c0 + tx];
  }
  __syncthreads();
  for (int r = ty; r < 64; r += 4) {
    out[(size_t)(c0 + r) * KT + k0 + tx] = tile[tx][r];
  }
}

// Accumulate QW quads (this wave's K-slice) of src into acc[16] (4 gates x 4
// units). src layout: [quad][64][4]. bg[g] = row base for gate g (unit jl at
// +jl*KT). Plain cached loads (L2/LLC dedup the cross-WG broadcast); chunked
// double-buffer to cover cache latency. Register shape proven spill-free
// (round 3: WRITE_SIZE ~1 MB at 128 VGPRs).
template <int QW, int CH, int KT>
__device__ __forceinline__ void accum4(const float* __restrict__ src, int q0,
                                       int kof0, const float* const bg[4],
                                       int lane, float acc[16]) {
  constexpr int NCH = QW / CH;
  float4 cur[CH], nxt[CH];
#pragma unroll
  for (int i = 0; i < CH; ++i)
    cur[i] = *(const float4*)(src + (size_t)(q0 + i) * 256 + lane * 4);
  for (int ch = 0; ch < NCH; ++ch) {
    const int qb = q0 + ch * CH;
    if (ch + 1 < NCH) {
#pragma unroll
      for (int i = 0; i < CH; ++i)
        nxt[i] = *(const float4*)(src + (size_t)(qb + CH + i) * 256 + lane * 4);
    }
#pragma unroll
    for (int i = 0; i < CH; ++i) {
      const int kof = kof0 + 4 * (qb + i);
      const float4 xv = cur[i];
#pragma unroll
      for (int g = 0; g < 4; ++g) {
#pragma unroll
        for (int jl = 0; jl < 4; ++jl) {
          const float4 w = *(const float4*)(bg[g] + (size_t)jl * KT + kof);
          float& a = acc[g * 4 + jl];
          a = fmaf(w.x, xv.x, a);
          a = fmaf(w.y, xv.y, a);
          a = fmaf(w.z, xv.z, a);
          a = fmaf(w.w, xv.w, a);
        }
      }
    }
#pragma unroll
    for (int i = 0; i < CH; ++i) cur[i] = nxt[i];
  }
}

// One pipelined LSTM layer. 256-thread WG owns hidden quad wg (4 units).
// lane = batch; 4 waves split K 4-ways; wave jl also owns unit jl's gates.
// Sync: agent-coherent flags; bulk h via normal cached loads (validated in
// round 5: write-once lines, read only after the producer's flag; dispatch
// acquire invalidates stale cache across graph replays).
// NWGP MUST equal the producer layer's NWG (round-6 bug: L5 polled 64 of
// L4's 128 flags and read unpublished upper-half h4).
template <int DIN, int H, int NWG, int NWGP, bool FIN, bool XCOH>
__device__ __forceinline__ void layer_body(
    int wg, int tid, const float* __restrict__ xin, float* __restrict__ hseq,
    const float* __restrict__ wuT, const float* __restrict__ bias,
    float* __restrict__ dout, unsigned* __restrict__ selfF,
    unsigned* __restrict__ prevF, float (*sZ)[16][64], float* sH) {
  constexpr int NQ2 = H / 4;
  constexpr int KT = DIN + H;
  constexpr int QW1 = DIN / 16;  // x-slice quads per wave
  constexpr int QW2 = H / 16;    // h-slice quads per wave
  constexpr int CH1 = (QW1 % 4 == 0) ? 4 : 2;
  constexpr int CH2 = (QW2 % 4 == 0) ? 4 : 2;
  constexpr int T = 256;
  static_assert(NWGP <= 128, "producer poll range must fit in tids 128..255");

  const int lane = tid & 63;
  const int wv = tid >> 6;  // 0..3

  const float* bg[4];
#pragma unroll
  for (int g = 0; g < 4; ++g) bg[g] = wuT + ((size_t)(g * H + wg * 4)) * KT;

  float bz[4];
#pragma unroll
  for (int g = 0; g < 4; ++g) bz[g] = bias[g * H + wg * 4 + wv];

  float cst = 0.f;

  for (int t = 0; t < T; ++t) {
    float acc[16];
#pragma unroll
    for (int c = 0; c < 16; ++c) acc[c] = 0.f;

    if (!XCOH) {
      // layer 0: x static — overlap input projection with waiting for peers
      accum4<QW1, CH1, KT>(xin + (size_t)t * (DIN / 4) * 256, wv * QW1, 0, bg,
                           lane, acc);
    }
    // threads 0..NWG-1 poll self flags (t-1); 128..128+NWGP-1 poll producer (t)
    if (t > 0 && tid < NWG) {
      while (__hip_atomic_load(&selfF[(t - 1) * NWG + tid], __ATOMIC_RELAXED,
                               AGENT) == 0u) {
        __builtin_amdgcn_s_sleep(4);
      }
    }
    if (XCOH && tid >= 128 && tid < 128 + NWGP) {
      while (__hip_atomic_load(&prevF[t * NWGP + (tid - 128)], __ATOMIC_RELAXED,
                               AGENT) == 0u) {
        __builtin_amdgcn_s_sleep(4);
      }
    }
    __syncthreads();
    asm volatile("" ::: "memory");  // no compiler hoist of loads above polls

    if (XCOH) {
      accum4<QW1, CH1, KT>(xin + (size_t)t * (DIN / 4) * 256, wv * QW1, 0, bg,
                           lane, acc);
    }
    if (t > 0) {
      accum4<QW2, CH2, KT>(hseq + (size_t)(t - 1) * NQ2 * 256, wv * QW2, DIN,
                           bg, lane, acc);
    }

    // 4-way K-split reduction
#pragma unroll
    for (int c = 0; c < 16; ++c) sZ[wv][c][lane] = acc[c];
    __syncthreads();

    float z[4];
#pragma unroll
    for (int g = 0; g < 4; ++g) {
      z[g] = bz[g];
#pragma unroll
      for (int k = 0; k < 4; ++k) z[g] += sZ[k][g * 4 + wv][lane];
    }
    const float ig = 1.f / (1.f + __expf(-z[0]));
    const float fg = 1.f / (1.f + __expf(-z[1]));
    const float gg = FIN ? tanhf(z[2]) : fmaxf(z[2], 0.f);
    const float og = 1.f / (1.f + __expf(-z[3]));
    cst = fg * cst + ig * gg;
    const float ca = FIN ? tanhf(cst) : fmaxf(cst, 0.f);
    const float h = og * ca;
    sH[lane * 4 + wv] = h;  // [b][jl]
    if (FIN && t == T - 1) dout[(size_t)lane * H + wg * 4 + wv] = h;
    __syncthreads();

    // wave 0 publishes the WG's 1 KB h-quad (agent write-through), then signal
    if (wv == 0) {
      const float4 v = *(const float4*)&sH[lane * 4];
      float* hw =
          hseq + (size_t)t * NQ2 * 256 + (size_t)wg * 256 + lane * 4;
      const u64 lo = ((u64)__float_as_uint(v.y) << 32) | __float_as_uint(v.x);
      const u64 hi = ((u64)__float_as_uint(v.w) << 32) | __float_as_uint(v.z);
      __hip_atomic_store((u64*)hw, lo, __ATOMIC_RELAXED, AGENT);
      __hip_atomic_store((u64*)hw + 1, hi, __ATOMIC_RELAXED, AGENT);
      asm volatile("s_waitcnt vmcnt(0)" ::: "memory");
      if (tid == 0)
        __hip_atomic_store(&selfF[t * NWG + wg], 1u, __ATOMIC_RELAXED, AGENT);
    }
  }
}

__global__ __launch_bounds__(256, 2) void lstm_fused(
    const float* __restrict__ xT, float* __restrict__ h0,
    float* __restrict__ h1, float* __restrict__ h2, float* __restrict__ h3,
    float* __restrict__ h4, float* __restrict__ h5,
    const float* __restrict__ wuT0, const float* __restrict__ wuT1,
    const float* __restrict__ wuT2, const float* __restrict__ wuT3,
    const float* __restrict__ wuT4, const float* __restrict__ wuT5,
    const float* __restrict__ b0, const float* __restrict__ b1,
    const float* __restrict__ b2, const float* __restrict__ b3,
    const float* __restrict__ b4, const float* __restrict__ b5,
    float* __restrict__ dout, unsigned* __restrict__ f0,
    unsigned* __restrict__ f1, unsigned* __restrict__ f2,
    unsigned* __restrict__ f3, unsigned* __restrict__ f4,
    unsigned* __restrict__ f5) {
  __shared__ float sZ[4][16][64];
  __shared__ float sH[256];
  const int b = blockIdx.x;
  const int tid = threadIdx.x;
  // heavy layers (L0, L4) first so they land one-per-CU
  if (b < 128) {
    layer_body<256, 512, 128, 0, false, false>(b, tid, xT, h0, wuT0, b0,
                                               nullptr, f0, nullptr, sZ, sH);
  } else if (b < 256) {
    layer_body<256, 512, 128, 64, false, true>(b - 128, tid, h3, h4, wuT4, b4,
                                               nullptr, f4, f3, sZ, sH);
  } else if (b < 320) {
    layer_body<512, 256, 64, 128, false, true>(b - 256, tid, h0, h1, wuT1, b1,
                                               nullptr, f1, f0, sZ, sH);
  } else if (b < 384) {
    layer_body<64, 256, 64, 16, false, true>(b - 320, tid, h2, h3, wuT3, b3,
                                             nullptr, f3, f2, sZ, sH);
  } else if (b < 448) {
    layer_body<512, 256, 64, 128, true, true>(b - 384, tid, h4, h5, wuT5, b5,
                                              dout, f5, f4, sZ, sH);
  } else {
    layer_body<256, 64, 16, 64, false, true>(b - 448, tid, h1, h2, wuT2, b2,
                                             nullptr, f2, f1, sZ, sH);
  }
}

extern "C" void kernel_launch(void* const* d_in, const int* in_sizes, int n_in,
                              void* d_out, int out_size, void* d_ws,
                              size_t ws_size, hipStream_t stream) {
  (void)in_sizes; (void)n_in; (void)out_size; (void)ws_size;
  const float* x = (const float*)d_in[0];
  const float* W[6];
  const float* U[6];
  const float* B[6];
  for (int l = 0; l < 6; ++l) {
    W[l] = (const float*)d_in[1 + 3 * l];
    U[l] = (const float*)d_in[2 + 3 * l];
    B[l] = (const float*)d_in[3 + 3 * l];
  }
  char* ws = (char*)d_ws;
  // flags: [T][NWG] per layer; NWG = 128,64,16,64,128,64
  unsigned* f0 = (unsigned*)ws;
  unsigned* f1 = f0 + 128 * 256;
  unsigned* f2 = f1 + 64 * 256;
  unsigned* f3 = f2 + 16 * 256;
  unsigned* f4 = f3 + 64 * 256;
  unsigned* f5 = f4 + 128 * 256;
  float* wuT0 = (float*)(ws + (1u << 20));
  float* wuT1 = wuT0 + (size_t)2048 * 768;
  float* wuT2 = wuT1 + (size_t)1024 * 768;
  float* wuT3 = wuT2 + (size_t)256 * 320;
  float* wuT4 = wuT3 + (size_t)1024 * 320;
  float* wuT5 = wuT4 + (size_t)2048 * 768;
  float* xT = (float*)(ws + (22u << 20));   // 16 MB
  float* h0 = (float*)(ws + (38u << 20));   // 32 MB
  float* h1 = (float*)(ws + (70u << 20));   // 16 MB
  float* h2 = (float*)(ws + (86u << 20));   // 4 MB
  float* h3 = (float*)(ws + (90u << 20));   // 16 MB
  float* h4 = (float*)(ws + (106u << 20));  // 32 MB
  float* h5 = (float*)(ws + (138u << 20));  // 16 MB (full T, no ring)

  hipMemsetAsync(f0, 0, 464 * 256 * sizeof(unsigned), stream);
  xpose_in<<<256, 256, 0, stream>>>(x, xT);
  pack_wu<<<dim3(32, 12), 256, 0, stream>>>(W[0], U[0], wuT0, 256, 512);
  pack_wu<<<dim3(16, 12), 256, 0, stream>>>(W[1], U[1], wuT1, 512, 256);
  pack_wu<<<dim3(4, 5), 256, 0, stream>>>(W[2], U[2], wuT2, 256, 64);
  pack_wu<<<dim3(16, 5), 256, 0, stream>>>(W[3], U[3], wuT3, 64, 256);
  pack_wu<<<dim3(32, 12), 256, 0, stream>>>(W[4], U[4], wuT4, 256, 512);
  pack_wu<<<dim3(16, 12), 256, 0, stream>>>(W[5], U[5], wuT5, 512, 256);

  lstm_fused<<<464, 256, 0, stream>>>(xT, h0, h1, h2, h3, h4, h5, wuT0, wuT1,
                                      wuT2, wuT3, wuT4, wuT5, B[0], B[1], B[2],
                                      B[3], B[4], B[5], (float*)d_out, f0, f1,
                                      f2, f3, f4, f5);
}